// Round 6
// baseline (473.872 us; speedup 1.0000x reference)
//
#include <hip/hip_runtime.h>

// Disable implicit FP contraction globally: the pairwise z^2/e^2 sums must
// round each product individually (numpy semantics). Explicit __fmaf_rn
// calls below still emit FMA where we *want* sgemm-style fused chains.
#pragma clang fp contract(off)

// VQ-VAE VectorQuantizer — bit-exact replication of the numpy fp32 pipeline:
//   d[r][j] = fl32( fl32(z2[r] + e2[j]) - 2*dot32[r][j] )
//   z2/e2: numpy pairwise-sum order (two 128-blocks, 8 accumulators each)
//   dot32: sequential-k fp32 FMA chain (BLAS sgemm per-element order)
//   argmin: first occurrence of the fp32 minimum (u64 key, low bits = index)
// Out layout (f32): [0..16777215] quantized_st, [16777216] vq_loss,
//                   [16777217..16842752] indices (as float).

#define NROWS   65536
#define DDIM    256
#define KCODES  1024
#define TILE_R  32
#define QSIZE   (NROWS * DDIM)          // 16777216
#define LOSS_OFF QSIZE
#define IDX_OFF (QSIZE + 1)

__device__ __forceinline__ unsigned long long pack_key(float s, unsigned j) {
    unsigned u = __float_as_uint(s);
    u = (u & 0x80000000u) ? ~u : (u | 0x80000000u);  // order-preserving map
    return ((unsigned long long)u << 32) | j;         // tie -> lower index (np first-min)
}

__device__ __forceinline__ float unpack_score(unsigned long long k) {
    unsigned u = (unsigned)(k >> 32);
    unsigned sb = (u & 0x80000000u) ? (u & 0x7FFFFFFFu) : ~u;
    return __uint_as_float(sb);
}

// numpy pairwise sum-of-squares over 128 contiguous floats (unrolled-8 path):
// r[j] = x[j]*x[j] + x[j+8]*x[j+8] + ... ; result = ((r0+r1)+(r2+r3))+((r4+r5)+(r6+r7))
__device__ __forceinline__ float pw128_sq(const float* __restrict__ x) {
    float r[8];
    #pragma unroll
    for (int j = 0; j < 8; ++j) r[j] = x[j] * x[j];
    for (int i = 8; i < 128; i += 8)
        #pragma unroll
        for (int j = 0; j < 8; ++j) r[j] += x[i + j] * x[i + j];
    return ((r[0] + r[1]) + (r[2] + r[3])) + ((r[4] + r[5]) + (r[6] + r[7]));
}

// Pack codebook to ETP[d4][j] (float4 over dims, k ascending inside),
// e2[j] = numpy-pairwise ||E_j||^2 in fp32. Also zero the loss accumulator.
__global__ void vq_pack(const float* __restrict__ E, float4* __restrict__ ETP,
                        float* __restrict__ e2, float* __restrict__ sum) {
    int j = blockIdx.x * blockDim.x + threadIdx.x;
    if (j == 0) *sum = 0.0f;
    if (j >= KCODES) return;
    const float* row = E + (size_t)j * DDIM;
    const float4* row4 = reinterpret_cast<const float4*>(row);
    for (int d4 = 0; d4 < DDIM / 4; ++d4) ETP[d4 * KCODES + j] = row4[d4];
    e2[j] = pw128_sq(row) + pw128_sq(row + 128);
}

__global__ __launch_bounds__(256, 2) void vq_main(
    const float* __restrict__ Z, const float4* __restrict__ ETP,
    const float* __restrict__ ee, const float* __restrict__ E,
    float* __restrict__ out, float* __restrict__ sum) {
    __shared__ float4 zs4[TILE_R][DDIM / 4];   // 32 KiB z tile
    __shared__ float zacc[TILE_R][16];         // pairwise partial accumulators
    __shared__ float zs2[TILE_R];              // np-ordered ||z||^2 per row
    __shared__ unsigned long long rmin[TILE_R];

    const int t = threadIdx.x;
    const long long rowbase = (long long)blockIdx.x * TILE_R;

    if (t < TILE_R) rmin[t] = ~0ULL;
    __syncthreads();

    // ---- stage z tile (coalesced float4) ----
    const float4* Zt = reinterpret_cast<const float4*>(Z + rowbase * DDIM);
    float4* zflat = &zs4[0][0];
    #pragma unroll
    for (int k = 0; k < 8; ++k) {
        int idx = t + 256 * k;
        zflat[idx] = Zt[idx];
    }
    __syncthreads();

    // ---- z2 per row, numpy pairwise order ----
    // thread t handles row r = t>>3, accumulator j = t&7, both 128-blocks.
    {
        int r = t >> 3, j = t & 7;
        const float* zr = reinterpret_cast<const float*>(&zs4[r][0]);
        float a0 = zr[j] * zr[j];
        float a1 = zr[128 + j] * zr[128 + j];
        for (int i = 8; i < 128; i += 8) {
            a0 += zr[i + j] * zr[i + j];
            a1 += zr[128 + i + j] * zr[128 + i + j];
        }
        zacc[r][j] = a0;
        zacc[r][8 + j] = a1;
    }
    __syncthreads();
    if (t < TILE_R) {
        const float* a = zacc[t];
        float c0 = ((a[0] + a[1]) + (a[2] + a[3])) + ((a[4] + a[5]) + (a[6] + a[7]));
        float c1 = ((a[8] + a[9]) + (a[10] + a[11])) + ((a[12] + a[13]) + (a[14] + a[15]));
        zs2[t] = c0 + c1;
    }
    __syncthreads();

    // ---- dots: thread t owns codes {t, t+256, t+512, t+768};
    //      strict sequential fp32 FMA over k = 0..255 ascending ----
    float acc0[TILE_R], acc1[TILE_R], acc2[TILE_R], acc3[TILE_R];
    #pragma unroll
    for (int r = 0; r < TILE_R; ++r) { acc0[r] = 0.f; acc1[r] = 0.f; acc2[r] = 0.f; acc3[r] = 0.f; }

    for (int d4 = 0; d4 < DDIM / 4; ++d4) {
        float4 ev0 = ETP[d4 * KCODES + t];
        float4 ev1 = ETP[d4 * KCODES + t + 256];
        float4 ev2 = ETP[d4 * KCODES + t + 512];
        float4 ev3 = ETP[d4 * KCODES + t + 768];
        #pragma unroll
        for (int r = 0; r < TILE_R; ++r) {
            float4 zv = zs4[r][d4];          // LDS broadcast, conflict-free
            float a0 = acc0[r], a1 = acc1[r], a2 = acc2[r], a3 = acc3[r];
            a0 = __fmaf_rn(zv.x, ev0.x, a0); a0 = __fmaf_rn(zv.y, ev0.y, a0);
            a0 = __fmaf_rn(zv.z, ev0.z, a0); a0 = __fmaf_rn(zv.w, ev0.w, a0);
            a1 = __fmaf_rn(zv.x, ev1.x, a1); a1 = __fmaf_rn(zv.y, ev1.y, a1);
            a1 = __fmaf_rn(zv.z, ev1.z, a1); a1 = __fmaf_rn(zv.w, ev1.w, a1);
            a2 = __fmaf_rn(zv.x, ev2.x, a2); a2 = __fmaf_rn(zv.y, ev2.y, a2);
            a2 = __fmaf_rn(zv.z, ev2.z, a2); a2 = __fmaf_rn(zv.w, ev2.w, a2);
            a3 = __fmaf_rn(zv.x, ev3.x, a3); a3 = __fmaf_rn(zv.y, ev3.y, a3);
            a3 = __fmaf_rn(zv.z, ev3.z, a3); a3 = __fmaf_rn(zv.w, ev3.w, a3);
            acc0[r] = a0; acc1[r] = a1; acc2[r] = a2; acc3[r] = a3;
        }
    }

    // ---- fp32 full-magnitude combine (replicates np ulp-256 rounding) + argmin ----
    float e0 = ee[t], e1 = ee[t + 256], e2v = ee[t + 512], e3 = ee[t + 768];
    #pragma unroll
    for (int r = 0; r < TILE_R; ++r) {
        float zr2 = zs2[r];
        float d0 = (zr2 + e0)  - 2.0f * acc0[r];
        float d1 = (zr2 + e1)  - 2.0f * acc1[r];
        float d2 = (zr2 + e2v) - 2.0f * acc2[r];
        float d3 = (zr2 + e3)  - 2.0f * acc3[r];
        unsigned long long best = pack_key(d0, (unsigned)t);
        unsigned long long k1   = pack_key(d1, (unsigned)(t + 256));
        unsigned long long k2   = pack_key(d2, (unsigned)(t + 512));
        unsigned long long k3   = pack_key(d3, (unsigned)(t + 768));
        if (k1 < best) best = k1;
        if (k2 < best) best = k2;
        if (k3 < best) best = k3;
        #pragma unroll
        for (int off = 1; off < 64; off <<= 1) {
            unsigned long long o = __shfl_xor(best, off);
            if (o < best) best = o;
        }
        if ((t & 63) == 0) atomicMin(&rmin[r], best);
    }
    __syncthreads();

    // ---- write quantized_st = codebook[argmin] ----
    float4* outq = reinterpret_cast<float4*>(out);
    #pragma unroll
    for (int k = 0; k < 8; ++k) {
        int idx = t + 256 * k;
        int r = idx >> 6, c4 = idx & 63;
        int code = (int)(rmin[r] & 0xFFFFFFFFu);
        float4 v = reinterpret_cast<const float4*>(E + (long long)code * DDIM)[c4];
        outq[rowbase * (DDIM / 4) + idx] = v;
    }
    // ---- indices as float ----
    if (t < TILE_R) {
        int code = (int)(rmin[t] & 0xFFFFFFFFu);
        out[(long long)IDX_OFF + rowbase + t] = (float)code;
    }
    // ---- loss partial: sum of min distances ----
    if (t == 0) {
        float part = 0.0f;
        #pragma unroll
        for (int r = 0; r < TILE_R; ++r) part += unpack_score(rmin[r]);
        atomicAdd(sum, part);
    }
}

__global__ void vq_finalize(const float* __restrict__ sum, float* __restrict__ out) {
    out[LOSS_OFF] = 1.25f * (*sum) / (float)QSIZE;
}

extern "C" void kernel_launch(void* const* d_in, const int* in_sizes, int n_in,
                              void* d_out, int out_size, void* d_ws, size_t ws_size,
                              hipStream_t stream) {
    // Robust input selection: z has QSIZE elements, codebook has KCODES*DDIM.
    const float* Z;
    const float* E;
    if (in_sizes[0] == QSIZE) { Z = (const float*)d_in[0]; E = (const float*)d_in[1]; }
    else                      { Z = (const float*)d_in[1]; E = (const float*)d_in[0]; }
    float* out = (float*)d_out;
    char* ws = (char*)d_ws;

    float* sum = (float*)ws;                                   // 16 B slot
    float4* ETP = (float4*)(ws + 16);                          // 1 MiB packed codebook
    float* ee = (float*)(ws + 16 + (size_t)(DDIM / 4) * KCODES * sizeof(float4));

    vq_pack<<<(KCODES + 255) / 256, 256, 0, stream>>>(E, ETP, ee, sum);
    vq_main<<<NROWS / TILE_R, 256, 0, stream>>>(Z, ETP, ee, E, out, sum);
    vq_finalize<<<1, 1, 0, stream>>>(sum, out);
}

// Round 7
// 433.862 us; speedup vs baseline: 1.0922x; 1.0922x over previous
//
#include <hip/hip_runtime.h>

// Disable implicit FP contraction: pairwise z^2/e^2 sums must round each
// product individually (numpy semantics). Explicit __fmaf_rn still fuses.
#pragma clang fp contract(off)

// VQ-VAE VectorQuantizer, two-tier:
//  Tier 1: bf16-split MFMA GEMM (zh*eh + zh*el + zl*eh) -> approx scores
//          S_j = ee[j] - 2*dot_j (error ~1.5e-6), fused per-row top-2.
//  Tier 2: rows with top-2 gap <= MARGIN re-scanned with the EXACT np fp32
//          pipeline (R6-proven): sequential-k fp32 FMA dot, pairwise norms,
//          full-magnitude combine fl(fl(z2+e2)-2dot), first-min tie-break.
//  np quantization bound Q~3.3e-5; MARGIN=1.5e-4 > 2Q+2delta (2.2x safety).
// Out (f32): [0..16777215] quantized_st, [16777216] loss, [16777217..] idx.
// The q region doubles as scratch for bf16 z (zah/zal) until vq_qwrite.

#define NROWS   65536
#define DDIM    256
#define KCODES  1024
#define QSIZE   (NROWS * DDIM)
#define LOSS_OFF QSIZE
#define IDX_OFF (QSIZE + 1)
#define MARGIN  1.5e-4f
#define RCAP    16384

typedef __bf16 bf16x8 __attribute__((ext_vector_type(8)));
typedef float f32x4 __attribute__((ext_vector_type(4)));
typedef unsigned int u32;
typedef unsigned long long u64;
typedef unsigned short u16;

__device__ __forceinline__ u32 omap(float s) {
    u32 u = __float_as_uint(s);
    return (u & 0x80000000u) ? ~u : (u | 0x80000000u);
}
__device__ __forceinline__ u64 pack_key(float s, u32 j) {
    return ((u64)omap(s) << 32) | j;
}

// numpy pairwise sum-of-squares over 128 floats (unrolled-8 path)
__device__ __forceinline__ float pw128_sq(const float* __restrict__ x) {
    float r[8];
    #pragma unroll
    for (int j = 0; j < 8; ++j) r[j] = x[j] * x[j];
    for (int i = 8; i < 128; i += 8)
        #pragma unroll
        for (int j = 0; j < 8; ++j) r[j] += x[i + j] * x[i + j];
    return ((r[0] + r[1]) + (r[2] + r[3])) + ((r[4] + r[5]) + (r[6] + r[7]));
}

// ---- codebook prep: ebh/ebl bf16 [ksub(32)][code(1024)][8], np-e2 ----
__global__ __launch_bounds__(256) void vq_pack_cb(
    const float* __restrict__ E, u16* __restrict__ ebh, u16* __restrict__ ebl,
    float* __restrict__ ee, float* __restrict__ sum, int* __restrict__ count) {
    int j = blockIdx.x * 256 + threadIdx.x;
    if (j == 0) { *sum = 0.0f; *count = 0; }
    if (j >= KCODES) return;
    const float* row = E + (size_t)j * DDIM;
    #pragma unroll
    for (int ks = 0; ks < 32; ++ks) {
        bf16x8 h8, l8;
        #pragma unroll
        for (int e = 0; e < 8; ++e) {
            float v = row[ks * 8 + e];
            __bf16 h = (__bf16)v;
            h8[e] = h;
            l8[e] = (__bf16)(v - (float)h);
        }
        *(bf16x8*)(ebh + ((size_t)ks * KCODES + j) * 8) = h8;
        *(bf16x8*)(ebl + ((size_t)ks * KCODES + j) * 8) = l8;
    }
    ee[j] = pw128_sq(row) + pw128_sq(row + 128);
}

// ---- z prep: zah/zal bf16 [ksub(32)][row(65536)][8] into q region; np-z2 ----
__global__ __launch_bounds__(256) void vq_cvt(
    const float* __restrict__ Z, u16* zah, u16* zal, float* __restrict__ z2) {
    __shared__ float zs[32 * 256];
    __shared__ float zacc[32][16];
    const int t = threadIdx.x;
    const size_t rowbase = (size_t)blockIdx.x * 32;
    const float4* Zt = (const float4*)(Z + rowbase * DDIM);
    #pragma unroll
    for (int k = 0; k < 8; ++k) ((float4*)zs)[t + 256 * k] = Zt[t + 256 * k];
    __syncthreads();
    {   // np pairwise z2 (R6-proven ordering)
        int r = t >> 3, j = t & 7;
        const float* zr = zs + r * 256;
        float a0 = zr[j] * zr[j], a1 = zr[128 + j] * zr[128 + j];
        for (int i = 8; i < 128; i += 8) {
            a0 += zr[i + j] * zr[i + j];
            a1 += zr[128 + i + j] * zr[128 + i + j];
        }
        zacc[r][j] = a0; zacc[r][8 + j] = a1;
    }
    __syncthreads();
    if (t < 32) {
        const float* a = zacc[t];
        float c0 = ((a[0] + a[1]) + (a[2] + a[3])) + ((a[4] + a[5]) + (a[6] + a[7]));
        float c1 = ((a[8] + a[9]) + (a[10] + a[11])) + ((a[12] + a[13]) + (a[14] + a[15]));
        z2[rowbase + t] = c0 + c1;
    }
    // bf16 split, k-major pieces: p = t + 256*i -> row=p&31, ksub=p>>5
    #pragma unroll
    for (int i = 0; i < 4; ++i) {
        int p = t + 256 * i;
        int row = p & 31, ks = p >> 5;
        bf16x8 h8, l8;
        #pragma unroll
        for (int e = 0; e < 8; ++e) {
            float v = zs[row * 256 + ks * 8 + e];
            __bf16 h = (__bf16)v;
            h8[e] = h;
            l8[e] = (__bf16)(v - (float)h);
        }
        size_t off = ((size_t)ks * NROWS + rowbase + row) * 8;
        *(bf16x8*)(zah + off) = h8;
        *(bf16x8*)(zal + off) = l8;
    }
}

// ---- tier-1 MFMA GEMM + fused top-2 / flag / loss ----
__global__ __launch_bounds__(256, 2) void vq_gemm(
    const u16* zah, const u16* zal,
    const u16* __restrict__ ebh, const u16* __restrict__ ebl,
    const float* __restrict__ ee, const float* __restrict__ z2,
    float* out, float* __restrict__ sum, int* __restrict__ count,
    int* __restrict__ list) {
    __shared__ char bs[8192];   // per-kstep B slab: hi 4KB + lo 4KB, XOR-swizzled
    const int t = threadIdx.x, w = t >> 6, l = t & 63;
    const int lr = l & 15, lg = l >> 4;
    const int rowbase = blockIdx.x * 128;

    // A fragments in registers: [rowfrag][kstep], hi/lo
    bf16x8 aH[2][8], aL[2][8];
    #pragma unroll
    for (int rf = 0; rf < 2; ++rf)
        #pragma unroll
        for (int s = 0; s < 8; ++s) {
            size_t off = ((size_t)(s * 4 + lg) * NROWS + rowbase + w * 32 + rf * 16 + lr) * 8;
            aH[rf][s] = *(const bf16x8*)(zah + off);
            aL[rf][s] = *(const bf16x8*)(zal + off);
        }

    u64 k1[2][4]; float s1[2][4], s2[2][4];
    #pragma unroll
    for (int rf = 0; rf < 2; ++rf)
        #pragma unroll
        for (int r = 0; r < 4; ++r) { k1[rf][r] = ~0ULL; s1[rf][r] = 1e30f; s2[rf][r] = 1e30f; }

    const int sc = t & 63, su = t >> 6;          // staging piece coords
    for (int ch = 0; ch < 16; ++ch) {
        const int chbase = ch * 64;
        f32x4 acc[2][4];
        #pragma unroll
        for (int rf = 0; rf < 2; ++rf)
            #pragma unroll
            for (int cf = 0; cf < 4; ++cf) acc[rf][cf] = 0.0f;

        uint4 rh = *(const uint4*)(ebh + ((size_t)(0 * 4 + su) * KCODES + chbase + sc) * 8);
        uint4 rl = *(const uint4*)(ebl + ((size_t)(0 * 4 + su) * KCODES + chbase + sc) * 8);
        #pragma unroll
        for (int s = 0; s < 8; ++s) {
            __syncthreads();
            int woff = (t * 16) ^ (su << 5);
            *(uint4*)(bs + woff) = rh;
            *(uint4*)(bs + 4096 + woff) = rl;
            __syncthreads();
            if (s < 7) {
                rh = *(const uint4*)(ebh + ((size_t)((s + 1) * 4 + su) * KCODES + chbase + sc) * 8);
                rl = *(const uint4*)(ebl + ((size_t)((s + 1) * 4 + su) * KCODES + chbase + sc) * 8);
            }
            #pragma unroll
            for (int cf = 0; cf < 4; ++cf) {
                int roff = ((lg * 64 + cf * 16 + lr) * 16) ^ (lg << 5);
                bf16x8 bh = *(const bf16x8*)(bs + roff);
                bf16x8 bl = *(const bf16x8*)(bs + 4096 + roff);
                #pragma unroll
                for (int rf = 0; rf < 2; ++rf) {
                    acc[rf][cf] = __builtin_amdgcn_mfma_f32_16x16x32_bf16(aH[rf][s], bh, acc[rf][cf], 0, 0, 0);
                    acc[rf][cf] = __builtin_amdgcn_mfma_f32_16x16x32_bf16(aH[rf][s], bl, acc[rf][cf], 0, 0, 0);
                    acc[rf][cf] = __builtin_amdgcn_mfma_f32_16x16x32_bf16(aL[rf][s], bh, acc[rf][cf], 0, 0, 0);
                }
            }
        }
        // chunk epilogue: per-lane running top-2 over its 4 codes
        #pragma unroll
        for (int cf = 0; cf < 4; ++cf) {
            int code = chbase + cf * 16 + lr;
            float e2c = ee[code];
            #pragma unroll
            for (int rf = 0; rf < 2; ++rf)
                #pragma unroll
                for (int r = 0; r < 4; ++r) {
                    float v = e2c - 2.0f * acc[rf][cf][r];
                    u64 k = pack_key(v, (u32)code);
                    if (k < k1[rf][r]) { s2[rf][r] = fminf(s2[rf][r], s1[rf][r]); s1[rf][r] = v; k1[rf][r] = k; }
                    else               { s2[rf][r] = fminf(s2[rf][r], v); }
                }
        }
    }
    // butterfly across the 16 lanes of each row group (lr bits only)
    #pragma unroll
    for (int off = 1; off < 16; off <<= 1) {
        #pragma unroll
        for (int rf = 0; rf < 2; ++rf)
            #pragma unroll
            for (int r = 0; r < 4; ++r) {
                u64 ok = __shfl_xor(k1[rf][r], off);
                float os1 = __shfl_xor(s1[rf][r], off);
                float os2 = __shfl_xor(s2[rf][r], off);
                bool other = ok < k1[rf][r];
                float worse = other ? s1[rf][r] : os1;
                if (other) { k1[rf][r] = ok; s1[rf][r] = os1; }
                s2[rf][r] = fminf(fminf(s2[rf][r], os2), worse);
            }
    }
    if (lr == 0) {
        float lsum = 0.0f;
        #pragma unroll
        for (int rf = 0; rf < 2; ++rf)
            #pragma unroll
            for (int r = 0; r < 4; ++r) {
                int row = rowbase + w * 32 + rf * 16 + lg * 4 + r;
                int code = (int)(k1[rf][r] & 1023ULL);
                out[(size_t)IDX_OFF + row] = (float)code;
                lsum += z2[row] + s1[rf][r];
                if (s2[rf][r] <= s1[rf][r] + MARGIN) {
                    int slot = atomicAdd(count, 1);
                    if (slot < RCAP) list[slot] = row;
                }
            }
        atomicAdd(sum, lsum);
    }
}

// ---- tier-2 exact np re-scan of flagged rows (R6-proven arithmetic) ----
__global__ __launch_bounds__(256) void vq_rescue(
    const float* __restrict__ Z, const float* __restrict__ E,
    const float* __restrict__ ee, const int* __restrict__ count,
    const int* __restrict__ list, float* out) {
    __shared__ float zrow[DDIM];
    __shared__ float za[16];
    __shared__ float zs2s;
    __shared__ u64 rmin;
    int n = *count; if (n > RCAP) n = RCAP;
    const int t = threadIdx.x;
    for (int i = blockIdx.x; i < n; i += gridDim.x) {
        int row = list[i];
        __syncthreads();
        if (t < 64) ((float4*)zrow)[t] = ((const float4*)(Z + (size_t)row * DDIM))[t];
        if (t == 0) rmin = ~0ULL;
        __syncthreads();
        if (t < 8) {   // np pairwise z2
            int j = t;
            float a0 = zrow[j] * zrow[j], a1 = zrow[128 + j] * zrow[128 + j];
            for (int k = 8; k < 128; k += 8) {
                a0 += zrow[k + j] * zrow[k + j];
                a1 += zrow[128 + k + j] * zrow[128 + k + j];
            }
            za[j] = a0; za[8 + j] = a1;
        }
        __syncthreads();
        if (t == 0) {
            float c0 = ((za[0] + za[1]) + (za[2] + za[3])) + ((za[4] + za[5]) + (za[6] + za[7]));
            float c1 = ((za[8] + za[9]) + (za[10] + za[11])) + ((za[12] + za[13]) + (za[14] + za[15]));
            zs2s = c0 + c1;
        }
        __syncthreads();
        float zr2 = zs2s;
        u64 best = ~0ULL;
        #pragma unroll
        for (int c = 0; c < 4; ++c) {
            int code = t + c * 256;
            const float4* er = (const float4*)(E + (size_t)code * DDIM);
            float a = 0.0f;
            for (int d4 = 0; d4 < 64; ++d4) {   // sequential-k fp32 FMA chain
                float4 ev = er[d4];
                float4 zv = ((const float4*)zrow)[d4];
                a = __fmaf_rn(zv.x, ev.x, a); a = __fmaf_rn(zv.y, ev.y, a);
                a = __fmaf_rn(zv.z, ev.z, a); a = __fmaf_rn(zv.w, ev.w, a);
            }
            float d = (zr2 + ee[code]) - 2.0f * a;   // np full-magnitude combine
            u64 k = pack_key(d, (u32)code);
            if (k < best) best = k;
        }
        #pragma unroll
        for (int off = 1; off < 64; off <<= 1) {
            u64 o = __shfl_xor(best, off);
            if (o < best) best = o;
        }
        if ((t & 63) == 0) atomicMin(&rmin, best);
        __syncthreads();
        if (t == 0) out[(size_t)IDX_OFF + row] = (float)(u32)(rmin & 0xFFFFFFFFu);
    }
}

// ---- gather codebook rows into quantized output (overwrites scratch) ----
__global__ __launch_bounds__(256) void vq_qwrite(const float* __restrict__ E, float* out) {
    __shared__ int qidx[32];
    const int t = threadIdx.x;
    const size_t rowbase = (size_t)blockIdx.x * 32;
    if (t < 32) qidx[t] = (int)out[(size_t)IDX_OFF + rowbase + t];
    __syncthreads();
    float4* outq = (float4*)out;
    #pragma unroll
    for (int k = 0; k < 8; ++k) {
        int idx = t + 256 * k;
        int r = idx >> 6, c4 = idx & 63;
        int code = qidx[r];
        outq[rowbase * 64 + idx] = ((const float4*)(E + (size_t)code * DDIM))[c4];
    }
}

__global__ void vq_finalize(const float* __restrict__ sum, float* __restrict__ out) {
    out[LOSS_OFF] = 1.25f * (*sum) / (float)QSIZE;
}

extern "C" void kernel_launch(void* const* d_in, const int* in_sizes, int n_in,
                              void* d_out, int out_size, void* d_ws, size_t ws_size,
                              hipStream_t stream) {
    const float* Z; const float* E;
    if (in_sizes[0] == QSIZE) { Z = (const float*)d_in[0]; E = (const float*)d_in[1]; }
    else                      { Z = (const float*)d_in[1]; E = (const float*)d_in[0]; }
    float* out = (float*)d_out;
    char* ws = (char*)d_ws;

    float* sum  = (float*)ws;                       // @0
    int*   count = (int*)(ws + 4);                  // @4
    float* ee   = (float*)(ws + 1024);              // 4 KB
    float* z2   = (float*)(ws + 8192);              // 256 KB
    u16*   ebh  = (u16*)(ws + 270336);              // 512 KB
    u16*   ebl  = (u16*)(ws + 270336 + 524288);     // 512 KB
    int*   list = (int*)(ws + 270336 + 1048576);    // 64 KB  (total ~1.38 MB)

    // bf16 z scratch lives in the q-output region until vq_qwrite
    u16* zah = (u16*)out;
    u16* zal = (u16*)out + (size_t)QSIZE;           // ushort offset = QSIZE

    vq_pack_cb<<<4, 256, 0, stream>>>(E, ebh, ebl, ee, sum, count);
    vq_cvt<<<NROWS / 32, 256, 0, stream>>>(Z, zah, zal, z2);
    vq_gemm<<<NROWS / 128, 256, 0, stream>>>(zah, zal, ebh, ebl, ee, z2, out, sum, count, list);
    vq_rescue<<<256, 256, 0, stream>>>(Z, E, ee, count, list, out);
    vq_qwrite<<<NROWS / 32, 256, 0, stream>>>(E, out);
    vq_finalize<<<1, 1, 0, stream>>>(sum, out);
}

// Round 8
// 270.232 us; speedup vs baseline: 1.7536x; 1.6055x over previous
//
#include <hip/hip_runtime.h>

// Disable implicit FP contraction: pairwise z^2/e^2 sums must round each
// product individually (numpy semantics). Explicit __fmaf_rn still fuses.
#pragma clang fp contract(off)

// VQ-VAE VectorQuantizer, two-tier:
//  Tier 1: bf16-split MFMA GEMM (zh*eh + zh*el + zl*eh) -> approx scores
//          S_j = ee[j] - 2*dot_j (error ~5e-8), fused per-row top-2.
//  Tier 2: rows with top-2 gap <= MARGIN re-scanned with the EXACT np fp32
//          pipeline (R6-proven), BATCHED 16 rows/block to amortize the
//          codebook read and make the FMA work throughput-bound.
//  np quantization bound Q~3.2e-5/score; MARGIN=1.5e-4 > 2Q (2.3x safety).
// Out (f32): [0..16777215] quantized_st, [16777216] loss, [16777217..] idx.
// The q region doubles as scratch for bf16 z (zah/zal) until vq_qwrite.

#define NROWS   65536
#define DDIM    256
#define KCODES  1024
#define QSIZE   (NROWS * DDIM)
#define LOSS_OFF QSIZE
#define IDX_OFF (QSIZE + 1)
#define MARGIN  1.5e-4f
#define RCAP    16384
#define RBATCH  16

typedef __bf16 bf16x8 __attribute__((ext_vector_type(8)));
typedef float f32x4 __attribute__((ext_vector_type(4)));
typedef unsigned int u32;
typedef unsigned long long u64;
typedef unsigned short u16;

__device__ __forceinline__ u32 omap(float s) {
    u32 u = __float_as_uint(s);
    return (u & 0x80000000u) ? ~u : (u | 0x80000000u);
}
__device__ __forceinline__ u64 pack_key(float s, u32 j) {
    return ((u64)omap(s) << 32) | j;
}

// numpy pairwise sum-of-squares over 128 floats (unrolled-8 path)
__device__ __forceinline__ float pw128_sq(const float* __restrict__ x) {
    float r[8];
    #pragma unroll
    for (int j = 0; j < 8; ++j) r[j] = x[j] * x[j];
    for (int i = 8; i < 128; i += 8)
        #pragma unroll
        for (int j = 0; j < 8; ++j) r[j] += x[i + j] * x[i + j];
    return ((r[0] + r[1]) + (r[2] + r[3])) + ((r[4] + r[5]) + (r[6] + r[7]));
}

// ---- codebook prep: ebh/ebl bf16 [ksub(32)][code(1024)][8], np-e2 ----
__global__ __launch_bounds__(256) void vq_pack_cb(
    const float* __restrict__ E, u16* __restrict__ ebh, u16* __restrict__ ebl,
    float* __restrict__ ee, float* __restrict__ sum, int* __restrict__ count) {
    int j = blockIdx.x * 256 + threadIdx.x;
    if (j == 0) { *sum = 0.0f; *count = 0; }
    if (j >= KCODES) return;
    const float* row = E + (size_t)j * DDIM;
    #pragma unroll
    for (int ks = 0; ks < 32; ++ks) {
        bf16x8 h8, l8;
        #pragma unroll
        for (int e = 0; e < 8; ++e) {
            float v = row[ks * 8 + e];
            __bf16 h = (__bf16)v;
            h8[e] = h;
            l8[e] = (__bf16)(v - (float)h);
        }
        *(bf16x8*)(ebh + ((size_t)ks * KCODES + j) * 8) = h8;
        *(bf16x8*)(ebl + ((size_t)ks * KCODES + j) * 8) = l8;
    }
    ee[j] = pw128_sq(row) + pw128_sq(row + 128);
}

// ---- z prep: zah/zal bf16 [ksub(32)][row(65536)][8] into q region; np-z2 ----
__global__ __launch_bounds__(256) void vq_cvt(
    const float* __restrict__ Z, u16* zah, u16* zal, float* __restrict__ z2) {
    __shared__ float zs[32 * 256];
    __shared__ float zacc[32][16];
    const int t = threadIdx.x;
    const size_t rowbase = (size_t)blockIdx.x * 32;
    const float4* Zt = (const float4*)(Z + rowbase * DDIM);
    #pragma unroll
    for (int k = 0; k < 8; ++k) ((float4*)zs)[t + 256 * k] = Zt[t + 256 * k];
    __syncthreads();
    {   // np pairwise z2 (R6-proven ordering)
        int r = t >> 3, j = t & 7;
        const float* zr = zs + r * 256;
        float a0 = zr[j] * zr[j], a1 = zr[128 + j] * zr[128 + j];
        for (int i = 8; i < 128; i += 8) {
            a0 += zr[i + j] * zr[i + j];
            a1 += zr[128 + i + j] * zr[128 + i + j];
        }
        zacc[r][j] = a0; zacc[r][8 + j] = a1;
    }
    __syncthreads();
    if (t < 32) {
        const float* a = zacc[t];
        float c0 = ((a[0] + a[1]) + (a[2] + a[3])) + ((a[4] + a[5]) + (a[6] + a[7]));
        float c1 = ((a[8] + a[9]) + (a[10] + a[11])) + ((a[12] + a[13]) + (a[14] + a[15]));
        z2[rowbase + t] = c0 + c1;
    }
    // bf16 split, k-major pieces: p = t + 256*i -> row=p&31, ksub=p>>5
    #pragma unroll
    for (int i = 0; i < 4; ++i) {
        int p = t + 256 * i;
        int row = p & 31, ks = p >> 5;
        bf16x8 h8, l8;
        #pragma unroll
        for (int e = 0; e < 8; ++e) {
            float v = zs[row * 256 + ks * 8 + e];
            __bf16 h = (__bf16)v;
            h8[e] = h;
            l8[e] = (__bf16)(v - (float)h);
        }
        size_t off = ((size_t)ks * NROWS + rowbase + row) * 8;
        *(bf16x8*)(zah + off) = h8;
        *(bf16x8*)(zal + off) = l8;
    }
}

// ---- tier-1 MFMA GEMM + fused top-2 / flag / loss ----
__global__ __launch_bounds__(256, 2) void vq_gemm(
    const u16* zah, const u16* zal,
    const u16* __restrict__ ebh, const u16* __restrict__ ebl,
    const float* __restrict__ ee, const float* __restrict__ z2,
    float* out, float* __restrict__ sum, int* __restrict__ count,
    int* __restrict__ list) {
    __shared__ char bs[8192];   // per-kstep B slab: hi 4KB + lo 4KB, XOR-swizzled
    const int t = threadIdx.x, w = t >> 6, l = t & 63;
    const int lr = l & 15, lg = l >> 4;
    const int rowbase = blockIdx.x * 128;

    // A fragments in registers: [rowfrag][kstep], hi/lo
    bf16x8 aH[2][8], aL[2][8];
    #pragma unroll
    for (int rf = 0; rf < 2; ++rf)
        #pragma unroll
        for (int s = 0; s < 8; ++s) {
            size_t off = ((size_t)(s * 4 + lg) * NROWS + rowbase + w * 32 + rf * 16 + lr) * 8;
            aH[rf][s] = *(const bf16x8*)(zah + off);
            aL[rf][s] = *(const bf16x8*)(zal + off);
        }

    u64 k1[2][4]; float s1[2][4], s2[2][4];
    #pragma unroll
    for (int rf = 0; rf < 2; ++rf)
        #pragma unroll
        for (int r = 0; r < 4; ++r) { k1[rf][r] = ~0ULL; s1[rf][r] = 1e30f; s2[rf][r] = 1e30f; }

    const int sc = t & 63, su = t >> 6;          // staging piece coords
    for (int ch = 0; ch < 16; ++ch) {
        const int chbase = ch * 64;
        f32x4 acc[2][4];
        #pragma unroll
        for (int rf = 0; rf < 2; ++rf)
            #pragma unroll
            for (int cf = 0; cf < 4; ++cf) acc[rf][cf] = 0.0f;

        uint4 rh = *(const uint4*)(ebh + ((size_t)(0 * 4 + su) * KCODES + chbase + sc) * 8);
        uint4 rl = *(const uint4*)(ebl + ((size_t)(0 * 4 + su) * KCODES + chbase + sc) * 8);
        #pragma unroll
        for (int s = 0; s < 8; ++s) {
            __syncthreads();
            int woff = (t * 16) ^ (su << 5);
            *(uint4*)(bs + woff) = rh;
            *(uint4*)(bs + 4096 + woff) = rl;
            __syncthreads();
            if (s < 7) {
                rh = *(const uint4*)(ebh + ((size_t)((s + 1) * 4 + su) * KCODES + chbase + sc) * 8);
                rl = *(const uint4*)(ebl + ((size_t)((s + 1) * 4 + su) * KCODES + chbase + sc) * 8);
            }
            #pragma unroll
            for (int cf = 0; cf < 4; ++cf) {
                int roff = ((lg * 64 + cf * 16 + lr) * 16) ^ (lg << 5);
                bf16x8 bh = *(const bf16x8*)(bs + roff);
                bf16x8 bl = *(const bf16x8*)(bs + 4096 + roff);
                #pragma unroll
                for (int rf = 0; rf < 2; ++rf) {
                    acc[rf][cf] = __builtin_amdgcn_mfma_f32_16x16x32_bf16(aH[rf][s], bh, acc[rf][cf], 0, 0, 0);
                    acc[rf][cf] = __builtin_amdgcn_mfma_f32_16x16x32_bf16(aH[rf][s], bl, acc[rf][cf], 0, 0, 0);
                    acc[rf][cf] = __builtin_amdgcn_mfma_f32_16x16x32_bf16(aL[rf][s], bh, acc[rf][cf], 0, 0, 0);
                }
            }
        }
        // chunk epilogue: per-lane running top-2 over its 4 codes
        #pragma unroll
        for (int cf = 0; cf < 4; ++cf) {
            int code = chbase + cf * 16 + lr;
            float e2c = ee[code];
            #pragma unroll
            for (int rf = 0; rf < 2; ++rf)
                #pragma unroll
                for (int r = 0; r < 4; ++r) {
                    float v = e2c - 2.0f * acc[rf][cf][r];
                    u64 k = pack_key(v, (u32)code);
                    if (k < k1[rf][r]) { s2[rf][r] = fminf(s2[rf][r], s1[rf][r]); s1[rf][r] = v; k1[rf][r] = k; }
                    else               { s2[rf][r] = fminf(s2[rf][r], v); }
                }
        }
    }
    // butterfly across the 16 lanes of each row group (lr bits only)
    #pragma unroll
    for (int off = 1; off < 16; off <<= 1) {
        #pragma unroll
        for (int rf = 0; rf < 2; ++rf)
            #pragma unroll
            for (int r = 0; r < 4; ++r) {
                u64 ok = __shfl_xor(k1[rf][r], off);
                float os1 = __shfl_xor(s1[rf][r], off);
                float os2 = __shfl_xor(s2[rf][r], off);
                bool other = ok < k1[rf][r];
                float worse = other ? s1[rf][r] : os1;
                if (other) { k1[rf][r] = ok; s1[rf][r] = os1; }
                s2[rf][r] = fminf(fminf(s2[rf][r], os2), worse);
            }
    }
    if (lr == 0) {
        float lsum = 0.0f;
        #pragma unroll
        for (int rf = 0; rf < 2; ++rf)
            #pragma unroll
            for (int r = 0; r < 4; ++r) {
                int row = rowbase + w * 32 + rf * 16 + lg * 4 + r;
                int code = (int)(k1[rf][r] & 1023ULL);
                out[(size_t)IDX_OFF + row] = (float)code;
                lsum += z2[row] + s1[rf][r];
                if (s2[rf][r] <= s1[rf][r] + MARGIN) {
                    int slot = atomicAdd(count, 1);
                    if (slot < RCAP) list[slot] = row;
                }
            }
        atomicAdd(sum, lsum);
    }
}

// ---- tier-2 exact np re-scan, BATCHED 16 rows/block (R6 arithmetic) ----
__global__ __launch_bounds__(256) void vq_rescue(
    const float* __restrict__ Z, const float* __restrict__ E,
    const float* __restrict__ ee, const int* __restrict__ count,
    const int* __restrict__ list, float* out) {
    __shared__ float zrow[RBATCH][DDIM];    // 16 KB
    __shared__ float zacc[RBATCH][16];
    __shared__ float z2s[RBATCH];
    __shared__ u64 rmin[RBATCH];
    __shared__ int rowid[RBATCH];
    int n = *count; if (n > RCAP) n = RCAP;
    const int t = threadIdx.x;
    const int base = blockIdx.x * RBATCH;
    if (base >= n) return;
    int nb = n - base; if (nb > RBATCH) nb = RBATCH;

    if (t < RBATCH) {
        rowid[t] = (t < nb) ? list[base + t] : 0;
        rmin[t] = ~0ULL;
    }
    __syncthreads();
    // stage z rows (coalesced float4): 16 rows x 64 float4
    #pragma unroll
    for (int i = 0; i < RBATCH * (DDIM / 4) / 256; ++i) {
        int p = t + 256 * i;
        int r = p >> 6, c4 = p & 63;
        if (r < nb) ((float4*)zrow[r])[c4] =
            ((const float4*)(Z + (size_t)rowid[r] * DDIM))[c4];
    }
    __syncthreads();
    // np pairwise z2 per row
    if (t < RBATCH * 8) {
        int r = t >> 3, j = t & 7;
        const float* zr = zrow[r];
        float a0 = zr[j] * zr[j], a1 = zr[128 + j] * zr[128 + j];
        for (int i = 8; i < 128; i += 8) {
            a0 += zr[i + j] * zr[i + j];
            a1 += zr[128 + i + j] * zr[128 + i + j];
        }
        zacc[r][j] = a0; zacc[r][8 + j] = a1;
    }
    __syncthreads();
    if (t < RBATCH) {
        const float* a = zacc[t];
        float c0 = ((a[0] + a[1]) + (a[2] + a[3])) + ((a[4] + a[5]) + (a[6] + a[7]));
        float c1 = ((a[8] + a[9]) + (a[10] + a[11])) + ((a[12] + a[13]) + (a[14] + a[15]));
        z2s[t] = c0 + c1;
    }
    __syncthreads();

    // dots: thread t owns codes {t,+256,+512,+768} x all RBATCH rows;
    // strict sequential fp32 FMA chain over k ascending per (row,code).
    float acc[4][RBATCH];
    #pragma unroll
    for (int c = 0; c < 4; ++c)
        #pragma unroll
        for (int r = 0; r < RBATCH; ++r) acc[c][r] = 0.0f;

    for (int d4 = 0; d4 < DDIM / 4; ++d4) {
        float4 ev[4];
        #pragma unroll
        for (int c = 0; c < 4; ++c)
            ev[c] = ((const float4*)(E + (size_t)(t + c * 256) * DDIM))[d4];
        #pragma unroll
        for (int r = 0; r < RBATCH; ++r) {
            float4 zv = ((const float4*)zrow[r])[d4];
            #pragma unroll
            for (int c = 0; c < 4; ++c) {
                float a = acc[c][r];
                a = __fmaf_rn(zv.x, ev[c].x, a); a = __fmaf_rn(zv.y, ev[c].y, a);
                a = __fmaf_rn(zv.z, ev[c].z, a); a = __fmaf_rn(zv.w, ev[c].w, a);
                acc[c][r] = a;
            }
        }
    }
    // per-row argmin: np full-magnitude combine + first-min tie-break
    float e2c[4];
    #pragma unroll
    for (int c = 0; c < 4; ++c) e2c[c] = ee[t + c * 256];
    #pragma unroll
    for (int r = 0; r < RBATCH; ++r) {
        float zr2 = z2s[r];
        u64 best = ~0ULL;
        #pragma unroll
        for (int c = 0; c < 4; ++c) {
            float d = (zr2 + e2c[c]) - 2.0f * acc[c][r];
            u64 k = pack_key(d, (u32)(t + c * 256));
            if (k < best) best = k;
        }
        #pragma unroll
        for (int off = 1; off < 64; off <<= 1) {
            u64 o = __shfl_xor(best, off);
            if (o < best) best = o;
        }
        if ((t & 63) == 0) atomicMin(&rmin[r], best);
    }
    __syncthreads();
    if (t < nb) out[(size_t)IDX_OFF + rowid[t]] = (float)(u32)(rmin[t] & 0xFFFFFFFFu);
}

// ---- gather codebook rows into quantized output (overwrites scratch) ----
__global__ __launch_bounds__(256) void vq_qwrite(const float* __restrict__ E, float* out) {
    __shared__ int qidx[32];
    const int t = threadIdx.x;
    const size_t rowbase = (size_t)blockIdx.x * 32;
    if (t < 32) qidx[t] = (int)out[(size_t)IDX_OFF + rowbase + t];
    __syncthreads();
    float4* outq = (float4*)out;
    #pragma unroll
    for (int k = 0; k < 8; ++k) {
        int idx = t + 256 * k;
        int r = idx >> 6, c4 = idx & 63;
        int code = qidx[r];
        outq[rowbase * 64 + idx] = ((const float4*)(E + (size_t)code * DDIM))[c4];
    }
}

__global__ void vq_finalize(const float* __restrict__ sum, float* __restrict__ out) {
    out[LOSS_OFF] = 1.25f * (*sum) / (float)QSIZE;
}

extern "C" void kernel_launch(void* const* d_in, const int* in_sizes, int n_in,
                              void* d_out, int out_size, void* d_ws, size_t ws_size,
                              hipStream_t stream) {
    const float* Z; const float* E;
    if (in_sizes[0] == QSIZE) { Z = (const float*)d_in[0]; E = (const float*)d_in[1]; }
    else                      { Z = (const float*)d_in[1]; E = (const float*)d_in[0]; }
    float* out = (float*)d_out;
    char* ws = (char*)d_ws;

    float* sum  = (float*)ws;                       // @0
    int*   count = (int*)(ws + 4);                  // @4
    float* ee   = (float*)(ws + 1024);              // 4 KB
    float* z2   = (float*)(ws + 8192);              // 256 KB
    u16*   ebh  = (u16*)(ws + 270336);              // 512 KB
    u16*   ebl  = (u16*)(ws + 270336 + 524288);     // 512 KB
    int*   list = (int*)(ws + 270336 + 1048576);    // 64 KB  (total ~1.38 MB)

    // bf16 z scratch lives in the q-output region until vq_qwrite
    u16* zah = (u16*)out;
    u16* zal = (u16*)out + (size_t)QSIZE;           // ushort offset = QSIZE

    vq_pack_cb<<<4, 256, 0, stream>>>(E, ebh, ebl, ee, sum, count);
    vq_cvt<<<NROWS / 32, 256, 0, stream>>>(Z, zah, zal, z2);
    vq_gemm<<<NROWS / 128, 256, 0, stream>>>(zah, zal, ebh, ebl, ee, z2, out, sum, count, list);
    vq_rescue<<<RCAP / RBATCH, 256, 0, stream>>>(Z, E, ee, count, list, out);
    vq_qwrite<<<NROWS / 32, 256, 0, stream>>>(E, out);
    vq_finalize<<<1, 1, 0, stream>>>(sum, out);
}